// Round 2
// baseline (1128.941 us; speedup 1.0000x reference)
//
#include <hip/hip_runtime.h>
#include <hip/hip_cooperative_groups.h>

namespace cg = cooperative_groups;

#define HH 1024
#define WW 2048
#define NN (HH*WW)
#define GRID 512
#define BLOCK 256
#define PXT (NN/(GRID*BLOCK))   // 16 pixels per thread
#define CHUNK (NN/GRID)         // 4096 pixels per block

// counters layout: [0]=psum[0] [1]=psum[1] [2]=inter[0] [3]=inter[1] [4]=uncl[0] [5]=uncl[1]

// XLA expands logistic(x) as 0.5 + 0.5*tanh(0.5*x) — match that form so the
// seed>0.5 boundary (== logit>0) resolves identically.
__device__ __forceinline__ float sigmoid_ref(float x) {
  #pragma clang fp contract(off)
  return 0.5f + 0.5f * tanhf(0.5f * x);
}

__global__ __launch_bounds__(BLOCK, 2)
void cluster_kernel(const float* __restrict__ pred,
                    int* __restrict__ out,                 // int32 labels
                    unsigned char* __restrict__ flags,     // bit0=mask bit1=uncl bit2=prop
                    float* __restrict__ pval,
                    int* __restrict__ pidx,
                    int* __restrict__ counters)
{
  #pragma clang fp contract(off)
  cg::grid_group gg = cg::this_grid();
  const int b = blockIdx.x, t = threadIdx.x;
  const int base = b * CHUNK;

  __shared__ float sv[BLOCK];
  __shared__ int   si[BLOCK];
  __shared__ int   sa[BLOCK];
  __shared__ int   sb[BLOCK];

  const float xstep = 2.0f / 2047.0f;   // jnp.linspace(0,2,2048) step, f32
  const float ystep = 1.0f / 1023.0f;   // jnp.linspace(0,1,1024) step, f32

  // ---- stage 0: zero counters ----
  if (b == 0 && t < 6) counters[t] = 0;
  gg.sync();

  // ---- stage 1: init flags/out, first argmax partials, mask count ----
  float bv = -1.0f; int bi = 0;
  int mcount = 0;
  for (int k = 0; k < PXT; ++k) {
    int i = base + t + k * BLOCK;
    float seed = sigmoid_ref(pred[6 * NN + i]);
    int m = (seed > 0.5f) ? 1 : 0;
    flags[i] = (unsigned char)(m * 3);   // mask | uncl
    out[i] = 0;
    mcount += m;
    float sc = m ? seed : 0.0f;
    if (sc > bv) { bv = sc; bi = i; }    // i increasing -> first max kept
  }
  sv[t] = bv; si[t] = bi; sa[t] = mcount; __syncthreads();
  for (int off = BLOCK / 2; off; off >>= 1) {
    if (t < off) {
      float v = sv[t + off]; int ix = si[t + off];
      if (v > sv[t] || (v == sv[t] && ix < si[t])) { sv[t] = v; si[t] = ix; }
      sa[t] += sa[t + off];
    }
    __syncthreads();
  }
  if (t == 0) { pval[b] = sv[0]; pidx[b] = si[0]; atomicAdd(&counters[4], sa[0]); }
  gg.sync();

  // ---- main greedy loop ----
  int count = 1;
  for (int it = 0; it < 4096; ++it) {
    const int p = it & 1;

    // ======== phase B ========
    int us = counters[4 + p];
    if (us <= 160) break;                     // cond: uncl.sum() > min_pixel
    if (b == 0 && t == 0) counters[4 + (p ^ 1)] = 0;

    // cross-block argmax reduce (GRID=512 partials, first-index tiebreak)
    {
      float v1 = pval[t];         int i1 = pidx[t];
      float v2 = pval[t + BLOCK]; int i2 = pidx[t + BLOCK];
      if (v2 > v1 || (v2 == v1 && i2 < i1)) { v1 = v2; i1 = i2; }
      sv[t] = v1; si[t] = i1;
    }
    __syncthreads();
    for (int off = BLOCK / 2; off; off >>= 1) {
      if (t < off) {
        float v = sv[t + off]; int ix = si[t + off];
        if (v > sv[t] || (v == sv[t] && ix < si[t])) { sv[t] = v; si[t] = ix; }
      }
      __syncthreads();
    }
    float sval = sv[0]; int sidx = si[0];
    __syncthreads();

    if (!(sval >= 0.5f)) break;               // go==false -> stop, no state change

    // center + sigma at seed pixel (recomputed identically by all threads)
    int scol = sidx & (WW - 1), srow = sidx >> 11;
    float cx = tanhf(pred[sidx])      + xstep * (float)scol;
    float cy = tanhf(pred[NN + sidx]) + ystep * (float)srow;
    float s0 = expf(pred[2 * NN + sidx] * 10.0f);
    float s1 = expf(pred[3 * NN + sidx] * 10.0f);

    int lps = 0, lin = 0;
    for (int k = 0; k < PXT; ++k) {
      int i = base + t + k * BLOCK;
      float ex = tanhf(pred[i])      + xstep * (float)(i & (WW - 1));
      float ey = tanhf(pred[NN + i]) + ystep * (float)(i >> 11);
      float dx = ex - cx, dy = ey - cy;
      float dsq = (dx * dx) * s0 + (dy * dy) * s1;
      float dist = expf(-dsq);
      unsigned char f = flags[i];
      int pr = ((dist > 0.5f) ? 1 : 0) & (f & 1);
      flags[i] = (unsigned char)((f & 3) | (pr << 2));
      lps += pr;
      lin += (pr && ((f >> 1) & 1) && (i != sidx)) ? 1 : 0;  // uncl2 & proposal
    }
    sa[t] = lps; sb[t] = lin; __syncthreads();
    for (int off = BLOCK / 2; off; off >>= 1) {
      if (t < off) { sa[t] += sa[t + off]; sb[t] += sb[t + off]; }
      __syncthreads();
    }
    if (t == 0) { atomicAdd(&counters[0 + p], sa[0]); atomicAdd(&counters[2 + p], sb[0]); }
    gg.sync();

    // ======== phase C ========
    int psum  = counters[0 + p];
    int inter = counters[2 + p];
    bool accept = (psum > 160) &&
                  ((float)inter / (float)(psum > 1 ? psum : 1) > 0.5f);
    if (b == 0 && t == 0) { counters[0 + (p ^ 1)] = 0; counters[2 + (p ^ 1)] = 0; }

    int lu = 0;
    bv = -1.0f; bi = 0;
    for (int k = 0; k < PXT; ++k) {
      int i = base + t + k * BLOCK;
      unsigned char f = flags[i];
      int pr = (f >> 2) & 1;
      int u  = (f >> 1) & 1;
      int nu = (u && !pr && (i != sidx)) ? 1 : 0;
      flags[i] = (unsigned char)((f & 1) | (nu << 1));
      lu += nu;
      if (accept && pr) out[i] = count;
      if (nu) {
        float seed = sigmoid_ref(pred[6 * NN + i]);
        if (seed > bv) { bv = seed; bi = i; }  // i increasing -> first max kept
      }
    }
    count += accept ? 1 : 0;

    sv[t] = bv; si[t] = bi; sa[t] = lu; __syncthreads();
    for (int off = BLOCK / 2; off; off >>= 1) {
      if (t < off) {
        float v = sv[t + off]; int ix = si[t + off];
        if (v > sv[t] || (v == sv[t] && ix < si[t])) { sv[t] = v; si[t] = ix; }
        sa[t] += sa[t + off];
      }
      __syncthreads();
    }
    if (t == 0) { pval[b] = sv[0]; pidx[b] = si[0]; atomicAdd(&counters[4 + (p ^ 1)], sa[0]); }
    gg.sync();
  }
}

extern "C" void kernel_launch(void* const* d_in, const int* in_sizes, int n_in,
                              void* d_out, int out_size, void* d_ws, size_t ws_size,
                              hipStream_t stream) {
  const float* pred = (const float*)d_in[0];
  int* out = (int*)d_out;

  char* ws = (char*)d_ws;
  unsigned char* flags = (unsigned char*)ws;                 // NN bytes
  float* pval    = (float*)(ws + NN);                        // GRID floats
  int*   pidx    = (int*)(ws + NN + GRID * sizeof(float));   // GRID ints
  int*   counters= (int*)(ws + NN + GRID * (sizeof(float) + sizeof(int))); // 6 ints

  void* args[] = { (void*)&pred, (void*)&out, (void*)&flags,
                   (void*)&pval, (void*)&pidx, (void*)&counters };
  hipLaunchCooperativeKernel((const void*)cluster_kernel, dim3(GRID), dim3(BLOCK),
                             args, 0, stream);
}